// Round 2
// baseline (403.085 us; speedup 1.0000x reference)
//
#include <hip/hip_runtime.h>

#define TT 2048
#define LL 288
#define CC 1024

typedef __attribute__((ext_vector_type(8))) short bf16x8;
typedef __attribute__((ext_vector_type(4))) float f32x4;
typedef __attribute__((ext_vector_type(4))) unsigned int u32x4;
typedef __attribute__((ext_vector_type(2))) unsigned int u32x2;
typedef __attribute__((ext_vector_type(4))) short s16x4;

__device__ __forceinline__ unsigned short f2bf(float f) {
  unsigned u = __float_as_uint(f);
  u += 0x7fffu + ((u >> 16) & 1u);
  return (unsigned short)(u >> 16);
}

__device__ __forceinline__ u32x2 pack4(f32x4 v) {
  u32x2 p;
  p.x = (unsigned)f2bf(v.x) | ((unsigned)f2bf(v.y) << 16);
  p.y = (unsigned)f2bf(v.z) | ((unsigned)f2bf(v.w) << 16);
  return p;
}

__device__ __forceinline__ f32x4 mfma16(bf16x8 a, bf16x8 b, f32x4 c) {
  return __builtin_amdgcn_mfma_f32_16x16x32_bf16(a, b, c, 0, 0, 0);
}

__device__ __forceinline__ bf16x8 as_bf(u32x4 u) {
  return __builtin_bit_cast(bf16x8, u);
}

typedef __attribute__((address_space(3))) const unsigned short* lds_cptr;

// ds_read_b64_tr_b16: each lane fetches 8B at ITS OWN addr; HW transposes
// within 16-lane groups. For a [4][16] bf16 row-major subtile at tile_base,
// pass addr = tile_base + (lane&15)*8; lane c elem j then holds tile[j][c].
__device__ __forceinline__ s16x4 tr16(const void* p) {
  s16x4 r;
  lds_cptr lp = (lds_cptr)p;
  asm volatile("ds_read_b64_tr_b16 %0, %1" : "=v"(r) : "v"(lp));
  return r;
}

// ---------------- Kernel 1: q = (x @ Wd_w^T + b) * 0.125, stored bf16 ----------------
// grid: 8192/64 = 128 blocks of 256 threads. Each wave: 16 rows x 288 cols.
__global__ __launch_bounds__(256, 2) void qproj(const float* __restrict__ x,
                                                const float* __restrict__ Ww,
                                                const float* __restrict__ Wb,
                                                unsigned short* __restrict__ q) {
  __shared__ unsigned short xl[64 * 64];   // [m][k] bf16, XOR-swizzled rows
  __shared__ unsigned short wl[LL * 64];   // [l][k] bf16, XOR-swizzled rows
  const int tid = threadIdx.x;
  const int lane = tid & 63;
  const int w = tid >> 6;
  const int g = lane >> 4;
  const int r = lane & 15;
  const int m0 = blockIdx.x * 64;

  f32x4 acc[18];
#pragma unroll
  for (int i = 0; i < 18; ++i) acc[i] = (f32x4)0.0f;

  char* xlb = (char*)xl;
  char* wlb = (char*)wl;

  for (int kb = 0; kb < CC; kb += 64) {
    __syncthreads();
#pragma unroll
    for (int j = 0; j < 4; ++j) {
      int idx = tid + 256 * j;
      int m = idx >> 4, k4 = idx & 15;
      f32x4 v = *(const f32x4*)(x + (long)(m0 + m) * CC + kb + k4 * 4);
      *(u32x2*)(xlb + m * 128 + ((k4 * 8) ^ ((m & 7) << 4))) = pack4(v);
    }
#pragma unroll
    for (int j = 0; j < 18; ++j) {
      int idx = tid + 256 * j;
      int l = idx >> 4, k4 = idx & 15;
      f32x4 v = *(const f32x4*)(Ww + (long)l * CC + kb + k4 * 4);
      *(u32x2*)(wlb + l * 128 + ((k4 * 8) ^ ((l & 7) << 4))) = pack4(v);
    }
    __syncthreads();
#pragma unroll
    for (int kc = 0; kc < 2; ++kc) {
      int koff = kc * 64 + g * 16;  // byte offset of this lane's k-chunk
      bf16x8 a = as_bf(*(const u32x4*)(xlb + (16 * w + r) * 128 + (koff ^ ((r & 7) << 4))));
#pragma unroll
      for (int nf = 0; nf < 18; ++nf) {
        int l = nf * 16 + r;
        bf16x8 bb = as_bf(*(const u32x4*)(wlb + l * 128 + (koff ^ ((l & 7) << 4))));
        acc[nf] = mfma16(a, bb, acc[nf]);
      }
    }
  }
  // epilogue: C layout col=lane&15, row=4*(lane>>4)+e
  const int rowb = m0 + 16 * w + 4 * g;
#pragma unroll
  for (int nf = 0; nf < 18; ++nf) {
    int col = nf * 16 + r;
    float bias = Wb[col];
#pragma unroll
    for (int e = 0; e < 4; ++e) {
      float qv = (acc[nf][e] + bias) * 0.125f;
      q[(long)(rowb + e) * LL + col] = f2bf(qv);
    }
  }
}

// ---------------- Kernel 2: causal softmax(q Wdkv^T) Wdkv ----------------
// grid: 4 batches * 32 q-tiles(64 rows) = 128 blocks of 256 threads.
// V LDS layout: subtiled [lblk=18][sgrp=16][s&3=4][l&15=16] bf16 (tr16-compatible).
__global__ __launch_bounds__(256, 2) void attn(const float* __restrict__ Wdkv,
                                               const unsigned short* __restrict__ q,
                                               float* __restrict__ out) {
  __shared__ unsigned short Vt[18 * 16 * 64];   // 36864 B
  __shared__ unsigned short Pl[4][16 * 64];     // per-wave P, XOR-swizzled
  const int tid = threadIdx.x;
  const int lane = tid & 63;
  const int w = tid >> 6;
  const int g = lane >> 4;
  const int r = lane & 15;
  const int b = blockIdx.x >> 5;
  const int tile = blockIdx.x & 31;
  const int q0 = tile * 64;

  char* vtb = (char*)Vt;
  char* plb = (char*)&Pl[w][0];

  // Q fragments in registers: A layout row=lane&15, k = kc*32 + 8*(lane>>4)
  const long qrow = (long)b * TT + q0 + 16 * w + r;
  bf16x8 qf[9];
#pragma unroll
  for (int kc = 0; kc < 9; ++kc)
    qf[kc] = as_bf(*(const u32x4*)(q + qrow * LL + kc * 32 + 8 * g));

  f32x4 o[18];
#pragma unroll
  for (int i = 0; i < 18; ++i) o[i] = (f32x4)0.0f;
  float mr[4], lr[4];
#pragma unroll
  for (int e = 0; e < 4; ++e) { mr[e] = -1e30f; lr[e] = 0.0f; }

  const float* Wp = Wdkv + (long)b * TT * LL;
  const int ntiles = tile + 1;
  const int wave_max = q0 + 16 * w + 15;
  const int s8i = tid >> 3;  // 0..31
  const int l4i = tid & 7;

  for (int st = 0; st < ntiles; ++st) {
    const int sb = st * 64;
    __syncthreads();
    // stage Wdkv[sb..sb+63][0..287] f32 -> bf16 subtiled LDS
#pragma unroll
    for (int j = 0; j < 18; ++j) {
      int s = (j & 1) * 32 + s8i;
      int l = ((j >> 1) * 8 + l4i) * 4;
      f32x4 v = *(const f32x4*)(Wp + (long)(sb + s) * LL + l);
      *(u32x2*)(vtb + ((l >> 4) * 2048 + (s >> 2) * 128 + (s & 3) * 32 + (l & 15) * 2)) = pack4(v);
    }
    __syncthreads();
    if (sb <= wave_max) {
      // ---- S = Q V^T  (16 q-rows x 64 s) ----
      f32x4 sa[4];
#pragma unroll
      for (int i = 0; i < 4; ++i) sa[i] = (f32x4)0.0f;
#pragma unroll
      for (int kc = 0; kc < 9; ++kc) {
        int kk = kc * 32 + 8 * g;          // l index of this lane's chunk
        int lblk = kk >> 4, lrem = kk & 15;
#pragma unroll
        for (int sf = 0; sf < 4; ++sf) {
          int sc = sf * 16 + r;            // s (col) index
          bf16x8 bb = as_bf(*(const u32x4*)(vtb + lblk * 2048 + (sc >> 2) * 128 + (sc & 3) * 32 + lrem * 2));
          sa[sf] = mfma16(qf[kc], bb, sa[sf]);
        }
      }
      // ---- mask + online softmax ----
      const int rqb = q0 + 16 * w + 4 * g;  // + e = global q row (within batch)
      float tm[4];
#pragma unroll
      for (int e = 0; e < 4; ++e) tm[e] = -1e30f;
#pragma unroll
      for (int sf = 0; sf < 4; ++sf) {
        int sg = sb + sf * 16 + r;
#pragma unroll
        for (int e = 0; e < 4; ++e) {
          if (sg > rqb + e) sa[sf][e] = -1e30f;
          tm[e] = fmaxf(tm[e], sa[sf][e]);
        }
      }
#pragma unroll
      for (int mm = 1; mm < 16; mm <<= 1)
#pragma unroll
        for (int e = 0; e < 4; ++e) tm[e] = fmaxf(tm[e], __shfl_xor(tm[e], mm));
      float al[4], rs[4];
#pragma unroll
      for (int e = 0; e < 4; ++e) {
        float mn = fmaxf(mr[e], tm[e]);
        al[e] = __expf(mr[e] - mn);
        mr[e] = mn;
        rs[e] = 0.0f;
      }
#pragma unroll
      for (int sf = 0; sf < 4; ++sf) {
#pragma unroll
        for (int e = 0; e < 4; ++e) {
          float p = __expf(sa[sf][e] - mr[e]);
          rs[e] += p;
          int row = 4 * g + e, col = sf * 16 + r;
          *(unsigned short*)(plb + row * 128 + ((col * 2) ^ ((row & 7) << 4))) = f2bf(p);
        }
      }
#pragma unroll
      for (int mm = 1; mm < 16; mm <<= 1)
#pragma unroll
        for (int e = 0; e < 4; ++e) rs[e] += __shfl_xor(rs[e], mm);
#pragma unroll
      for (int e = 0; e < 4; ++e) lr[e] = lr[e] * al[e] + rs[e];
#pragma unroll
      for (int nf = 0; nf < 18; ++nf)
#pragma unroll
        for (int e = 0; e < 4; ++e) o[nf][e] *= al[e];
      // ---- O += P V ----
      bf16x8 pa0 = as_bf(*(const u32x4*)(plb + r * 128 + (((0 * 32 + 8 * g) * 2) ^ ((r & 7) << 4))));
      bf16x8 pa1 = as_bf(*(const u32x4*)(plb + r * 128 + (((1 * 32 + 8 * g) * 2) ^ ((r & 7) << 4))));
      asm volatile("" : "+v"(pa0), "+v"(pa1));  // keep P resolved before tr16 region
#pragma unroll
      for (int kc2 = 0; kc2 < 2; ++kc2) {
        bf16x8 pa = (kc2 == 0) ? pa0 : pa1;
        // group g consumes s = kc2*32 + 8g + j  ->  s-group (kc2*8 + 2g) and +1.
        // per-lane tr16 addr = subtile base + (lane&15)*8.
        const int base0 = kc2 * 1024 + g * 256 + r * 8;
#pragma unroll
        for (int gg = 0; gg < 6; ++gg) {
          s16x4 t[6];
#pragma unroll
          for (int i = 0; i < 3; ++i) {
            int nf = gg * 3 + i;
            t[2 * i] = tr16(vtb + nf * 2048 + base0);
            t[2 * i + 1] = tr16(vtb + nf * 2048 + base0 + 128);
          }
          asm volatile("s_waitcnt lgkmcnt(0)" ::: "memory");
          __builtin_amdgcn_sched_barrier(0);
#pragma unroll
          for (int i = 0; i < 3; ++i) {
            int nf = gg * 3 + i;
            s16x4 t0 = t[2 * i], t1 = t[2 * i + 1];
            bf16x8 bb;
            bb[0] = t0[0]; bb[1] = t0[1]; bb[2] = t0[2]; bb[3] = t0[3];
            bb[4] = t1[0]; bb[5] = t1[1]; bb[6] = t1[2]; bb[7] = t1[3];
            o[nf] = mfma16(pa, bb, o[nf]);
          }
        }
      }
    }
  }
  // ---- epilogue: O / l ----
  const long trow = (long)b * TT + q0 + 16 * w + 4 * g;
#pragma unroll
  for (int nf = 0; nf < 18; ++nf) {
    int col = nf * 16 + r;
#pragma unroll
    for (int e = 0; e < 4; ++e) {
      out[(trow + e) * LL + col] = o[nf][e] / lr[e];
    }
  }
}

extern "C" void kernel_launch(void* const* d_in, const int* in_sizes, int n_in,
                              void* d_out, int out_size, void* d_ws, size_t ws_size,
                              hipStream_t stream) {
  const float* x = (const float*)d_in[0];
  const float* Wdkv = (const float*)d_in[1];
  const float* Ww = (const float*)d_in[2];
  const float* Wb = (const float*)d_in[3];
  float* outp = (float*)d_out;
  unsigned short* qws = (unsigned short*)d_ws;  // 8192*288 bf16 = 4.5 MB

  qproj<<<128, 256, 0, stream>>>(x, Ww, Wb, qws);
  attn<<<4 * 32, 256, 0, stream>>>(Wdkv, qws, outp);
}

// Round 3
// 170.122 us; speedup vs baseline: 2.3694x; 2.3694x over previous
//
#include <hip/hip_runtime.h>

#define TT 2048
#define LL 288
#define CC 1024
#define SLOT_F 18560  // floats per partial slot: m[64] + l[64] + O[64*288]

typedef __attribute__((ext_vector_type(8))) short bf16x8;
typedef __attribute__((ext_vector_type(4))) float f32x4;
typedef __attribute__((ext_vector_type(4))) unsigned int u32x4;
typedef __attribute__((ext_vector_type(2))) unsigned int u32x2;
typedef __attribute__((ext_vector_type(4))) short s16x4;

__device__ __forceinline__ unsigned short f2bf(float f) {
  unsigned u = __float_as_uint(f);
  u += 0x7fffu + ((u >> 16) & 1u);
  return (unsigned short)(u >> 16);
}

__device__ __forceinline__ u32x2 pack4(f32x4 v) {
  u32x2 p;
  p.x = (unsigned)f2bf(v.x) | ((unsigned)f2bf(v.y) << 16);
  p.y = (unsigned)f2bf(v.z) | ((unsigned)f2bf(v.w) << 16);
  return p;
}

__device__ __forceinline__ f32x4 mfma16(bf16x8 a, bf16x8 b, f32x4 c) {
  return __builtin_amdgcn_mfma_f32_16x16x32_bf16(a, b, c, 0, 0, 0);
}

__device__ __forceinline__ bf16x8 as_bf(u32x4 u) {
  return __builtin_bit_cast(bf16x8, u);
}

typedef __attribute__((address_space(3))) const unsigned short* lds_cptr;

// ds_read_b64_tr_b16: each lane fetches 8B at ITS OWN addr (tile_base + (lane&15)*8);
// HW transposes within 16-lane groups: lane c elem j holds tile[j][c] of a [4][16] bf16 subtile.
__device__ __forceinline__ s16x4 tr16(const void* p) {
  s16x4 r;
  lds_cptr lp = (lds_cptr)p;
  asm volatile("ds_read_b64_tr_b16 %0, %1" : "=v"(r) : "v"(lp));
  return r;
}

// ---------------- Kernel 1: q = (x @ Wd_w^T + b) * 0.125, stored bf16 ----------------
// grid: 128 row-blocks x 3 col-blocks = 384 blocks of 256 threads.
// block = 64 rows x 96 cols; wave = 16 rows x 96 cols (6 frags).
__global__ __launch_bounds__(256, 2) void qproj(const float* __restrict__ x,
                                                const float* __restrict__ Ww,
                                                const float* __restrict__ Wb,
                                                unsigned short* __restrict__ q) {
  __shared__ unsigned short xl[64 * 64];   // [m][k] bf16, XOR-swizzled rows (8KB)
  __shared__ unsigned short wl[96 * 64];   // [l][k] bf16, XOR-swizzled rows (12KB)
  const int tid = threadIdx.x;
  const int lane = tid & 63;
  const int w = tid >> 6;
  const int g = lane >> 4;
  const int r = lane & 15;
  const int m0 = (blockIdx.x / 3) * 64;
  const int c0 = (blockIdx.x % 3) * 96;

  f32x4 acc[6];
#pragma unroll
  for (int i = 0; i < 6; ++i) acc[i] = (f32x4)0.0f;

  char* xlb = (char*)xl;
  char* wlb = (char*)wl;

  for (int kb = 0; kb < CC; kb += 64) {
    __syncthreads();
#pragma unroll
    for (int j = 0; j < 4; ++j) {
      int idx = tid + 256 * j;
      int m = idx >> 4, k4 = idx & 15;
      f32x4 v = *(const f32x4*)(x + (long)(m0 + m) * CC + kb + k4 * 4);
      *(u32x2*)(xlb + m * 128 + ((k4 * 8) ^ ((m & 7) << 4))) = pack4(v);
    }
#pragma unroll
    for (int j = 0; j < 6; ++j) {
      int idx = tid + 256 * j;
      int l = idx >> 4, k4 = idx & 15;
      f32x4 v = *(const f32x4*)(Ww + (long)(c0 + l) * CC + kb + k4 * 4);
      *(u32x2*)(wlb + l * 128 + ((k4 * 8) ^ ((l & 7) << 4))) = pack4(v);
    }
    __syncthreads();
#pragma unroll
    for (int kc = 0; kc < 2; ++kc) {
      int koff = kc * 64 + g * 16;
      bf16x8 a = as_bf(*(const u32x4*)(xlb + (16 * w + r) * 128 + (koff ^ ((r & 7) << 4))));
#pragma unroll
      for (int nf = 0; nf < 6; ++nf) {
        int l = nf * 16 + r;
        bf16x8 bb = as_bf(*(const u32x4*)(wlb + l * 128 + (koff ^ ((l & 7) << 4))));
        acc[nf] = mfma16(a, bb, acc[nf]);
      }
    }
  }
  const int rowb = m0 + 16 * w + 4 * g;
#pragma unroll
  for (int nf = 0; nf < 6; ++nf) {
    int col = c0 + nf * 16 + r;
    float bias = Wb[col];
#pragma unroll
    for (int e = 0; e < 4; ++e) {
      float qv = (acc[nf][e] + bias) * 0.125f;
      q[(long)(rowb + e) * LL + col] = f2bf(qv);
    }
  }
}

// ---------------- Kernel 2: causal softmax(q Wdkv^T) Wdkv, flash split-s ----------------
// grid: 4 batches * SPB chunk-slots. Chunk = up to CH s-tiles (64 rows each) of the
// causal range of one 64-row q-tile. Single-chunk tiles write out directly;
// multi-chunk tiles write raw (m,l,O) partials to ws, combined by reduce_k.
__global__ __launch_bounds__(256, 2) void attn(const float* __restrict__ Wdkv,
                                               const unsigned short* __restrict__ q,
                                               float* __restrict__ out,
                                               float* __restrict__ partial,
                                               int CH, int SPB) {
  __shared__ unsigned short Vt[18 * 16 * 64];   // 36864 B, subtiled tr16 layout
  __shared__ unsigned short Pl[4][16 * 64];     // per-wave P, XOR-swizzled
  const int tid = threadIdx.x;
  const int lane = tid & 63;
  const int w = tid >> 6;
  const int g = lane >> 4;
  const int r = lane & 15;

  const int bid = blockIdx.x;
  const int b = bid / SPB;
  int rem = bid - b * SPB;
  int t = 0, base = 0;
  for (;;) {
    int nch = (t + CH) / CH;  // ceil((t+1)/CH)
    if (rem < base + nch) break;
    base += nch;
    ++t;
  }
  const int c = rem - base;
  const int nch_t = (t + CH) / CH;
  const bool direct = (nch_t == 1);
  const int q0 = t * 64;
  const int st0 = c * CH;
  const int st1 = min((c + 1) * CH, t + 1);

  char* vtb = (char*)Vt;
  char* plb = (char*)&Pl[w][0];

  // Q fragments: A layout row=lane&15, k = kc*32 + 8*(lane>>4)
  const long qrow = (long)b * TT + q0 + 16 * w + r;
  bf16x8 qf[9];
#pragma unroll
  for (int kc = 0; kc < 9; ++kc)
    qf[kc] = as_bf(*(const u32x4*)(q + qrow * LL + kc * 32 + 8 * g));

  f32x4 o[18];
#pragma unroll
  for (int i = 0; i < 18; ++i) o[i] = (f32x4)0.0f;
  float mr[4], lr[4];
#pragma unroll
  for (int e = 0; e < 4; ++e) { mr[e] = -1e30f; lr[e] = 0.0f; }

  const float* Wp = Wdkv + (long)b * TT * LL;
  const int s8i = tid >> 3;
  const int l4i = tid & 7;

  for (int st = st0; st < st1; ++st) {
    const int sb = st * 64;
    __syncthreads();
#pragma unroll
    for (int j = 0; j < 18; ++j) {
      int s = (j & 1) * 32 + s8i;
      int l = ((j >> 1) * 8 + l4i) * 4;
      f32x4 v = *(const f32x4*)(Wp + (long)(sb + s) * LL + l);
      *(u32x2*)(vtb + ((l >> 4) * 2048 + (s >> 2) * 128 + (s & 3) * 32 + (l & 15) * 2)) = pack4(v);
    }
    __syncthreads();
    // ---- S = Q V^T ----
    f32x4 sa[4];
#pragma unroll
    for (int i = 0; i < 4; ++i) sa[i] = (f32x4)0.0f;
#pragma unroll
    for (int kc = 0; kc < 9; ++kc) {
      int kk = kc * 32 + 8 * g;
      int lblk = kk >> 4, lrem = kk & 15;
#pragma unroll
      for (int sf = 0; sf < 4; ++sf) {
        int sc = sf * 16 + r;
        bf16x8 bb = as_bf(*(const u32x4*)(vtb + lblk * 2048 + (sc >> 2) * 128 + (sc & 3) * 32 + lrem * 2));
        sa[sf] = mfma16(qf[kc], bb, sa[sf]);
      }
    }
    // ---- mask + online softmax ----
    const int rqb = q0 + 16 * w + 4 * g;
    float tm[4];
#pragma unroll
    for (int e = 0; e < 4; ++e) tm[e] = -1e30f;
#pragma unroll
    for (int sf = 0; sf < 4; ++sf) {
      int sg = sb + sf * 16 + r;
#pragma unroll
      for (int e = 0; e < 4; ++e) {
        if (sg > rqb + e) sa[sf][e] = -1e30f;
        tm[e] = fmaxf(tm[e], sa[sf][e]);
      }
    }
#pragma unroll
    for (int mm = 1; mm < 16; mm <<= 1)
#pragma unroll
      for (int e = 0; e < 4; ++e) tm[e] = fmaxf(tm[e], __shfl_xor(tm[e], mm));
    float al[4], rs[4];
#pragma unroll
    for (int e = 0; e < 4; ++e) {
      float mn = fmaxf(mr[e], tm[e]);
      al[e] = __expf(mr[e] - mn);
      mr[e] = mn;
      rs[e] = 0.0f;
    }
#pragma unroll
    for (int sf = 0; sf < 4; ++sf) {
#pragma unroll
      for (int e = 0; e < 4; ++e) {
        float p = __expf(sa[sf][e] - mr[e]);
        rs[e] += p;
        int row = 4 * g + e, col = sf * 16 + r;
        *(unsigned short*)(plb + row * 128 + ((col * 2) ^ ((row & 7) << 4))) = f2bf(p);
      }
    }
#pragma unroll
    for (int mm = 1; mm < 16; mm <<= 1)
#pragma unroll
      for (int e = 0; e < 4; ++e) rs[e] += __shfl_xor(rs[e], mm);
#pragma unroll
    for (int e = 0; e < 4; ++e) lr[e] = lr[e] * al[e] + rs[e];
#pragma unroll
    for (int nf = 0; nf < 18; ++nf)
#pragma unroll
      for (int e = 0; e < 4; ++e) o[nf][e] *= al[e];
    // ---- O += P V ----
    bf16x8 pa0 = as_bf(*(const u32x4*)(plb + r * 128 + (((0 * 32 + 8 * g) * 2) ^ ((r & 7) << 4))));
    bf16x8 pa1 = as_bf(*(const u32x4*)(plb + r * 128 + (((1 * 32 + 8 * g) * 2) ^ ((r & 7) << 4))));
    asm volatile("" : "+v"(pa0), "+v"(pa1));
#pragma unroll
    for (int kc2 = 0; kc2 < 2; ++kc2) {
      bf16x8 pa = (kc2 == 0) ? pa0 : pa1;
      const int base0 = kc2 * 1024 + g * 256 + r * 8;
#pragma unroll
      for (int gg = 0; gg < 6; ++gg) {
        s16x4 tq[6];
#pragma unroll
        for (int i = 0; i < 3; ++i) {
          int nf = gg * 3 + i;
          tq[2 * i] = tr16(vtb + nf * 2048 + base0);
          tq[2 * i + 1] = tr16(vtb + nf * 2048 + base0 + 128);
        }
        asm volatile("s_waitcnt lgkmcnt(0)" ::: "memory");
        __builtin_amdgcn_sched_barrier(0);
#pragma unroll
        for (int i = 0; i < 3; ++i) {
          int nf = gg * 3 + i;
          s16x4 t0 = tq[2 * i], t1 = tq[2 * i + 1];
          bf16x8 bb;
          bb[0] = t0[0]; bb[1] = t0[1]; bb[2] = t0[2]; bb[3] = t0[3];
          bb[4] = t1[0]; bb[5] = t1[1]; bb[6] = t1[2]; bb[7] = t1[3];
          o[nf] = mfma16(pa, bb, o[nf]);
        }
      }
    }
  }
  // ---- epilogue ----
  if (direct) {
    const long trow = (long)b * TT + q0 + 16 * w + 4 * g;
#pragma unroll
    for (int nf = 0; nf < 18; ++nf) {
      int col = nf * 16 + r;
#pragma unroll
      for (int e = 0; e < 4; ++e) out[(trow + e) * LL + col] = o[nf][e] / lr[e];
    }
  } else {
    float* sp = partial + (size_t)(b * SPB + rem) * SLOT_F;
    const int rloc = 16 * w + 4 * g;
    if (r == 0) {
#pragma unroll
      for (int e = 0; e < 4; ++e) {
        sp[rloc + e] = mr[e];
        sp[64 + rloc + e] = lr[e];
      }
    }
    float* Op = sp + 128;
#pragma unroll
    for (int nf = 0; nf < 18; ++nf) {
      int col = nf * 16 + r;
#pragma unroll
      for (int e = 0; e < 4; ++e) Op[(rloc + e) * LL + col] = o[nf][e];
    }
  }
}

// ---------------- Kernel 3: combine partials ----------------
// grid: 4 * (32 - CH) blocks of 256 threads; block = (b, t) with t >= CH.
__global__ __launch_bounds__(256, 2) void reduce_k(const float* __restrict__ partial,
                                                   float* __restrict__ out,
                                                   int CH, int SPB) {
  const int nmt = 32 - CH;
  const int b = blockIdx.x / nmt;
  const int t = CH + blockIdx.x % nmt;
  int base = 0;
  for (int u = 0; u < t; ++u) base += (u + CH) / CH;
  const int nch = (t + CH) / CH;
  const float* sp0 = partial + (size_t)(b * SPB + base) * SLOT_F;

  const int row = threadIdx.x >> 2;
  const int cs = threadIdx.x & 3;

  float M = -1e30f;
  for (int i = 0; i < nch; ++i) M = fmaxf(M, sp0[(size_t)i * SLOT_F + row]);

  float L = 0.0f;
  f32x4 acc[18];
#pragma unroll
  for (int i = 0; i < 18; ++i) acc[i] = (f32x4)0.0f;

  for (int i = 0; i < nch; ++i) {
    const float* sp = sp0 + (size_t)i * SLOT_F;
    float f = __expf(sp[row] - M);
    L += sp[64 + row] * f;
    const float* Op = sp + 128 + row * LL;
#pragma unroll
    for (int qd = 0; qd < 18; ++qd) {
      f32x4 v = *(const f32x4*)(Op + qd * 16 + cs * 4);
      acc[qd] += f * v;
    }
  }
  const float rl = 1.0f / L;
  float* Or = out + ((size_t)b * TT + t * 64 + row) * LL;
#pragma unroll
  for (int qd = 0; qd < 18; ++qd) {
    f32x4 v = acc[qd] * rl;
    *(f32x4*)(Or + qd * 16 + cs * 4) = v;
  }
}

extern "C" void kernel_launch(void* const* d_in, const int* in_sizes, int n_in,
                              void* d_out, int out_size, void* d_ws, size_t ws_size,
                              hipStream_t stream) {
  const float* x = (const float*)d_in[0];
  const float* Wdkv = (const float*)d_in[1];
  const float* Ww = (const float*)d_in[2];
  const float* Wb = (const float*)d_in[3];
  float* outp = (float*)d_out;
  unsigned short* qws = (unsigned short*)d_ws;  // 8192*288 bf16

  size_t qb = (size_t)8192 * 288 * 2;
  size_t qb_al = (qb + 255) & ~(size_t)255;

  // pick finest split CH that fits ws (deterministic: depends only on ws_size)
  int CH = 32, SPB = 32;
  for (int ch = 4; ch < 32; ch *= 2) {
    int spb = 0;
    for (int t = 0; t < 32; ++t) spb += (t + ch) / ch;
    if (qb_al + (size_t)4 * spb * (SLOT_F * 4) <= ws_size) { CH = ch; SPB = spb; break; }
  }
  float* partial = (float*)((char*)d_ws + qb_al);

  qproj<<<384, 256, 0, stream>>>(x, Ww, Wb, qws);
  attn<<<4 * SPB, 256, 0, stream>>>(Wdkv, qws, outp, partial, CH, SPB);
  if (CH < 32) reduce_k<<<4 * (32 - CH), 256, 0, stream>>>(partial, outp, CH, SPB);
}

// Round 4
// 87.106 us; speedup vs baseline: 4.6275x; 1.9530x over previous
//
#include <hip/hip_runtime.h>

#define TT 2048
#define LL 288
#define CC 1024
#define SLOTB 37376  // bytes per partial slot: m[64]f32 + l[64]f32 + O[64*288]bf16

typedef __attribute__((ext_vector_type(8))) short bf16x8;
typedef __attribute__((ext_vector_type(4))) float f32x4;
typedef __attribute__((ext_vector_type(4))) unsigned int u32x4;
typedef __attribute__((ext_vector_type(2))) unsigned int u32x2;
typedef __attribute__((ext_vector_type(4))) short s16x4;

__device__ __forceinline__ unsigned short f2bf(float f) {
  unsigned u = __float_as_uint(f);
  u += 0x7fffu + ((u >> 16) & 1u);
  return (unsigned short)(u >> 16);
}

__device__ __forceinline__ u32x2 pack4(f32x4 v) {
  u32x2 p;
  p.x = (unsigned)f2bf(v.x) | ((unsigned)f2bf(v.y) << 16);
  p.y = (unsigned)f2bf(v.z) | ((unsigned)f2bf(v.w) << 16);
  return p;
}

__device__ __forceinline__ f32x4 mfma16(bf16x8 a, bf16x8 b, f32x4 c) {
  return __builtin_amdgcn_mfma_f32_16x16x32_bf16(a, b, c, 0, 0, 0);
}

__device__ __forceinline__ bf16x8 as_bf(u32x4 u) {
  return __builtin_bit_cast(bf16x8, u);
}

typedef __attribute__((address_space(3))) const unsigned short* lds_cptr;
typedef __attribute__((address_space(1))) const void* gvp;
typedef __attribute__((address_space(3))) void* svp;

// ds_read_b64_tr_b16: each lane fetches 8B at ITS OWN addr (tile_base + (lane&15)*8);
// HW transposes within 16-lane groups: lane c elem j holds tile[j][c] of a [4][16] bf16 subtile.
__device__ __forceinline__ s16x4 tr16(const void* p) {
  s16x4 r;
  lds_cptr lp = (lds_cptr)p;
  asm volatile("ds_read_b64_tr_b16 %0, %1" : "=v"(r) : "v"(lp));
  return r;
}

// async global->LDS, 16B/lane; LDS dest = wave-uniform base + lane*16 (linear).
__device__ __forceinline__ void gll16(const void* g, void* l) {
  __builtin_amdgcn_global_load_lds((gvp)g, (svp)l, 16, 0, 0);
}

// ---------------- Kernel 0: f32 -> bf16 convert (x, Wdkv, Ww) ----------------
// 8 elems/thread; grid 5392*256 covers exactly (8388608+2359296+294912)/8.
__global__ __launch_bounds__(256) void tobf16(const float* __restrict__ x,
                                              const float* __restrict__ wdkv,
                                              const float* __restrict__ ww,
                                              unsigned short* __restrict__ xB,
                                              unsigned short* __restrict__ wdkvB,
                                              unsigned short* __restrict__ wwB) {
  long i8 = (long)blockIdx.x * 256 + threadIdx.x;
  const float* src;
  unsigned short* dst;
  long k;
  if (i8 < 1048576L) { src = x; dst = xB; k = i8; }
  else if (i8 < 1343488L) { src = wdkv; dst = wdkvB; k = i8 - 1048576L; }
  else { src = ww; dst = wwB; k = i8 - 1343488L; }
  f32x4 a = *(const f32x4*)(src + k * 8);
  f32x4 c = *(const f32x4*)(src + k * 8 + 4);
  u32x2 p0 = pack4(a), p1 = pack4(c);
  u32x4 o;
  o.x = p0.x; o.y = p0.y; o.z = p1.x; o.w = p1.y;
  *(u32x4*)(dst + k * 8) = o;
}

// ---------------- Kernel 1: q = (xB @ WwB^T + b) * 0.125, stored bf16 ----------------
// grid: 128 row-blocks x 3 col-blocks = 384 blocks of 256 threads.
// gll-staged, double-buffered, XOR-swizzle via pre-swizzled global source.
__global__ __launch_bounds__(256, 4) void qproj(const unsigned short* __restrict__ xB,
                                                const unsigned short* __restrict__ wwB,
                                                const float* __restrict__ Wb,
                                                unsigned short* __restrict__ q) {
  __shared__ unsigned short xl[2][64 * 64];   // [m][k] bf16, swizzled (2x8KB)
  __shared__ unsigned short wl[2][96 * 64];   // [l][k] bf16, swizzled (2x12KB)
  const int tid = threadIdx.x;
  const int lane = tid & 63;
  const int w = tid >> 6;
  const int g = lane >> 4;
  const int r = lane & 15;
  const int m0 = (blockIdx.x / 3) * 64;
  const int c0 = (blockIdx.x % 3) * 96;

  // lane source offset: row (lane>>3) within 8-row group, 16B k-chunk (lane&7),
  // inverse-swizzled so that linear LDS write yields byte ^ ((row&7)<<4) layout.
  const int o_i = (lane >> 3) * 2048 + (((lane & 7) * 16) ^ ((lane >> 3) << 4));

  f32x4 acc[6];
#pragma unroll
  for (int i = 0; i < 6; ++i) acc[i] = (f32x4)0.0f;

  const char* xsrc = (const char*)xB + (long)m0 * 2048;
  const char* wsrc = (const char*)wwB + (long)c0 * 2048;

#define QPROJ_ISSUE(kb2, cb)                                            \
  {                                                                     \
    char* xd = (char*)&xl[cb][0];                                       \
    char* wd = (char*)&wl[cb][0];                                       \
    _Pragma("unroll") for (int jj = 0; jj < 2; ++jj) {                  \
      int j = 2 * w + jj;                                               \
      gll16(xsrc + (long)j * 16384 + (kb2) + o_i, xd + j * 1024);       \
    }                                                                   \
    _Pragma("unroll") for (int jj = 0; jj < 3; ++jj) {                  \
      int j = 3 * w + jj;                                               \
      gll16(wsrc + (long)j * 16384 + (kb2) + o_i, wd + j * 1024);       \
    }                                                                   \
  }

  QPROJ_ISSUE(0, 0);
  for (int ks = 0; ks < 16; ++ks) {
    const int cb = ks & 1;
    if (ks < 15) {
      QPROJ_ISSUE((ks + 1) * 128, cb ^ 1);
      asm volatile("s_waitcnt vmcnt(5)" ::: "memory");
    } else {
      asm volatile("s_waitcnt vmcnt(0)" ::: "memory");
    }
    __builtin_amdgcn_s_barrier();
    __builtin_amdgcn_sched_barrier(0);
    const char* xlb = (const char*)&xl[cb][0];
    const char* wlb = (const char*)&wl[cb][0];
#pragma unroll
    for (int kc = 0; kc < 2; ++kc) {
      int koff = kc * 64 + g * 16;
      bf16x8 a = as_bf(*(const u32x4*)(xlb + (16 * w + r) * 128 + (koff ^ ((r & 7) << 4))));
#pragma unroll
      for (int nf = 0; nf < 6; ++nf) {
        int l = nf * 16 + r;
        bf16x8 bb = as_bf(*(const u32x4*)(wlb + l * 128 + (koff ^ ((l & 7) << 4))));
        acc[nf] = mfma16(a, bb, acc[nf]);
      }
    }
    __builtin_amdgcn_sched_barrier(0);
    __builtin_amdgcn_s_barrier();
    __builtin_amdgcn_sched_barrier(0);
  }
  const int rowb = m0 + 16 * w + 4 * g;
#pragma unroll
  for (int nf = 0; nf < 6; ++nf) {
    int col = c0 + nf * 16 + r;
    float bias = Wb[col];
#pragma unroll
    for (int e = 0; e < 4; ++e) {
      float qv = (acc[nf][e] + bias) * 0.125f;
      q[(long)(rowb + e) * LL + col] = f2bf(qv);
    }
  }
}

// ---------------- Kernel 2: causal softmax(q Wdkv^T) Wdkv, flash split-s ----------------
// gll-staged double-buffered V; subtiled tr16 LDS layout fed by pre-permuted source addrs.
__global__ __launch_bounds__(256, 2) void attn(const unsigned short* __restrict__ wdkvB,
                                               const unsigned short* __restrict__ q,
                                               float* __restrict__ out,
                                               char* __restrict__ partial,
                                               int CH, int SPB) {
  __shared__ unsigned short Vt[2][18 * 16 * 64];  // 2x36864 B
  __shared__ unsigned short Pl[4][16 * 64];       // 8192 B
  const int tid = threadIdx.x;
  const int lane = tid & 63;
  const int w = tid >> 6;
  const int g = lane >> 4;
  const int r = lane & 15;

  const int bid = blockIdx.x;
  const int b = bid / SPB;
  int rem = bid - b * SPB;
  int t = 0, base = 0;
  for (;;) {
    int nch = (t + CH) / CH;
    if (rem < base + nch) break;
    base += nch;
    ++t;
  }
  const int c = rem - base;
  const bool direct = ((t + CH) / CH == 1);
  const int q0 = t * 64;
  const int st0 = c * CH;
  const int st1 = min((c + 1) * CH, t + 1);

  char* plb = (char*)&Pl[w][0];

  // per-lane gll source offsets for the subtiled layout:
  // instr j in [0,36): LDS bytes [1024j,1024j+1024) = lblk j>>1, s-half j&1.
  // lane i: s=(j&1)*32+4*(i>>3)+((i>>1)&3), l=(j>>1)*16+(i&1)*8.
  int off[9];
#pragma unroll
  for (int jj = 0; jj < 9; ++jj) {
    int j = 9 * w + jj;
    int s = (j & 1) * 32 + 4 * (lane >> 3) + ((lane >> 1) & 3);
    int l = (j >> 1) * 16 + (lane & 1) * 8;
    off[jj] = s * (LL * 2) + l * 2;
  }
  const char* wsrc = (const char*)wdkvB + (long)b * TT * (LL * 2);

  // Q fragments: A layout row=lane&15, k = kc*32 + 8*(lane>>4)
  const long qrow = (long)b * TT + q0 + 16 * w + r;
  bf16x8 qf[9];
#pragma unroll
  for (int kc = 0; kc < 9; ++kc)
    qf[kc] = as_bf(*(const u32x4*)(q + qrow * LL + kc * 32 + 8 * g));

  f32x4 o[18];
#pragma unroll
  for (int i = 0; i < 18; ++i) o[i] = (f32x4)0.0f;
  float mr[4], lr[4];
#pragma unroll
  for (int e = 0; e < 4; ++e) { mr[e] = -1e30f; lr[e] = 0.0f; }

#define ATTN_ISSUE(sb, cb)                                       \
  {                                                              \
    const char* src = wsrc + (long)(sb) * (LL * 2);              \
    char* dst = (char*)&Vt[cb][0] + w * 9216;                    \
    _Pragma("unroll") for (int jj = 0; jj < 9; ++jj)             \
        gll16(src + off[jj], dst + jj * 1024);                   \
  }

  ATTN_ISSUE(st0 * 64, 0);
  for (int st = st0; st < st1; ++st) {
    const int sb = st * 64;
    const int cb = (st - st0) & 1;
    if (st + 1 < st1) {
      ATTN_ISSUE((st + 1) * 64, cb ^ 1);
      asm volatile("s_waitcnt vmcnt(9)" ::: "memory");
    } else {
      asm volatile("s_waitcnt vmcnt(0)" ::: "memory");
    }
    __builtin_amdgcn_s_barrier();
    __builtin_amdgcn_sched_barrier(0);
    const char* vtb = (const char*)&Vt[cb][0];
    // ---- S = Q V^T ----
    f32x4 sa[4];
#pragma unroll
    for (int i = 0; i < 4; ++i) sa[i] = (f32x4)0.0f;
#pragma unroll
    for (int kc = 0; kc < 9; ++kc) {
      int kk = kc * 32 + 8 * g;
      int lblk = kk >> 4, lrem = kk & 15;
#pragma unroll
      for (int sf = 0; sf < 4; ++sf) {
        int sc = sf * 16 + r;
        bf16x8 bb = as_bf(*(const u32x4*)(vtb + lblk * 2048 + (sc >> 2) * 128 + (sc & 3) * 32 + lrem * 2));
        sa[sf] = mfma16(qf[kc], bb, sa[sf]);
      }
    }
    // ---- mask + online softmax ----
    const int rqb = q0 + 16 * w + 4 * g;
    float tm[4];
#pragma unroll
    for (int e = 0; e < 4; ++e) tm[e] = -1e30f;
#pragma unroll
    for (int sf = 0; sf < 4; ++sf) {
      int sg = sb + sf * 16 + r;
#pragma unroll
      for (int e = 0; e < 4; ++e) {
        if (sg > rqb + e) sa[sf][e] = -1e30f;
        tm[e] = fmaxf(tm[e], sa[sf][e]);
      }
    }
#pragma unroll
    for (int mm = 1; mm < 16; mm <<= 1)
#pragma unroll
      for (int e = 0; e < 4; ++e) tm[e] = fmaxf(tm[e], __shfl_xor(tm[e], mm));
    float al[4], rs[4];
#pragma unroll
    for (int e = 0; e < 4; ++e) {
      float mn = fmaxf(mr[e], tm[e]);
      al[e] = __expf(mr[e] - mn);
      mr[e] = mn;
      rs[e] = 0.0f;
    }
#pragma unroll
    for (int sf = 0; sf < 4; ++sf) {
#pragma unroll
      for (int e = 0; e < 4; ++e) {
        float p = __expf(sa[sf][e] - mr[e]);
        rs[e] += p;
        int row = 4 * g + e, col = sf * 16 + r;
        *(unsigned short*)(plb + row * 128 + ((col * 2) ^ ((row & 7) << 4))) = f2bf(p);
      }
    }
#pragma unroll
    for (int mm = 1; mm < 16; mm <<= 1)
#pragma unroll
      for (int e = 0; e < 4; ++e) rs[e] += __shfl_xor(rs[e], mm);
#pragma unroll
    for (int e = 0; e < 4; ++e) lr[e] = lr[e] * al[e] + rs[e];
#pragma unroll
    for (int nf = 0; nf < 18; ++nf)
#pragma unroll
      for (int e = 0; e < 4; ++e) o[nf][e] *= al[e];
    // ---- O += P V ----
    bf16x8 pa0 = as_bf(*(const u32x4*)(plb + r * 128 + (((0 * 32 + 8 * g) * 2) ^ ((r & 7) << 4))));
    bf16x8 pa1 = as_bf(*(const u32x4*)(plb + r * 128 + (((1 * 32 + 8 * g) * 2) ^ ((r & 7) << 4))));
    asm volatile("" : "+v"(pa0), "+v"(pa1));
#pragma unroll
    for (int kc2 = 0; kc2 < 2; ++kc2) {
      bf16x8 pa = (kc2 == 0) ? pa0 : pa1;
      const int base0 = kc2 * 1024 + g * 256 + r * 8;
#pragma unroll
      for (int gg = 0; gg < 6; ++gg) {
        s16x4 tq[6];
#pragma unroll
        for (int i = 0; i < 3; ++i) {
          int nf = gg * 3 + i;
          tq[2 * i] = tr16(vtb + nf * 2048 + base0);
          tq[2 * i + 1] = tr16(vtb + nf * 2048 + base0 + 128);
        }
        asm volatile("s_waitcnt lgkmcnt(0)" ::: "memory");
        __builtin_amdgcn_sched_barrier(0);
#pragma unroll
        for (int i = 0; i < 3; ++i) {
          int nf = gg * 3 + i;
          s16x4 t0 = tq[2 * i], t1 = tq[2 * i + 1];
          bf16x8 bb;
          bb[0] = t0[0]; bb[1] = t0[1]; bb[2] = t0[2]; bb[3] = t0[3];
          bb[4] = t1[0]; bb[5] = t1[1]; bb[6] = t1[2]; bb[7] = t1[3];
          o[nf] = mfma16(pa, bb, o[nf]);
        }
      }
    }
    __builtin_amdgcn_sched_barrier(0);
    __builtin_amdgcn_s_barrier();
    __builtin_amdgcn_sched_barrier(0);
  }
  // ---- epilogue ----
  if (direct) {
    const long trow = (long)b * TT + q0 + 16 * w + 4 * g;
#pragma unroll
    for (int nf = 0; nf < 18; ++nf) {
      int col = nf * 16 + r;
#pragma unroll
      for (int e = 0; e < 4; ++e) out[(trow + e) * LL + col] = o[nf][e] / lr[e];
    }
  } else {
    char* sp = partial + (size_t)(b * SPB + rem) * SLOTB;
    const int rloc = 16 * w + 4 * g;
    if (r == 0) {
#pragma unroll
      for (int e = 0; e < 4; ++e) {
        ((float*)sp)[rloc + e] = mr[e];
        ((float*)(sp + 256))[rloc + e] = lr[e];
      }
    }
    unsigned short* Op = (unsigned short*)(sp + 512);
#pragma unroll
    for (int nf = 0; nf < 18; ++nf) {
      int col = nf * 16 + r;
#pragma unroll
      for (int e = 0; e < 4; ++e) Op[(rloc + e) * LL + col] = f2bf(o[nf][e]);
    }
  }
}

// ---------------- Kernel 3: combine partials (bf16 O) ----------------
__global__ __launch_bounds__(256, 2) void reduce_k(const char* __restrict__ partial,
                                                   float* __restrict__ out,
                                                   int CH, int SPB) {
  const int nmt = 32 - CH;
  const int b = blockIdx.x / nmt;
  const int t = CH + blockIdx.x % nmt;
  int base = 0;
  for (int u = 0; u < t; ++u) base += (u + CH) / CH;
  const int nch = (t + CH) / CH;
  const char* sp0 = partial + (size_t)(b * SPB + base) * SLOTB;

  const int row = threadIdx.x >> 2;
  const int colb = (threadIdx.x & 3) * 72;

  float M = -1e30f;
  for (int i = 0; i < nch; ++i)
    M = fmaxf(M, ((const float*)(sp0 + (size_t)i * SLOTB))[row]);

  float L = 0.0f;
  float acc[72];
#pragma unroll
  for (int i = 0; i < 72; ++i) acc[i] = 0.0f;

  for (int i = 0; i < nch; ++i) {
    const char* sp = sp0 + (size_t)i * SLOTB;
    float f = __expf(((const float*)sp)[row] - M);
    L += ((const float*)(sp + 256))[row] * f;
    const unsigned short* Op = (const unsigned short*)(sp + 512) + row * LL + colb;
#pragma unroll
    for (int v8 = 0; v8 < 9; ++v8) {
      u32x4 pv = *(const u32x4*)(Op + v8 * 8);
      const unsigned short* pu = (const unsigned short*)&pv;
#pragma unroll
      for (int e = 0; e < 8; ++e)
        acc[v8 * 8 + e] += f * __uint_as_float((unsigned)pu[e] << 16);
    }
  }
  const float rl = 1.0f / L;
  float* Or = out + ((size_t)b * TT + t * 64 + row) * LL + colb;
#pragma unroll
  for (int v4 = 0; v4 < 18; ++v4) {
    f32x4 v;
#pragma unroll
    for (int e = 0; e < 4; ++e) v[e] = acc[v4 * 4 + e] * rl;
    *(f32x4*)(Or + v4 * 4) = v;
  }
}

extern "C" void kernel_launch(void* const* d_in, const int* in_sizes, int n_in,
                              void* d_out, int out_size, void* d_ws, size_t ws_size,
                              hipStream_t stream) {
  const float* x = (const float*)d_in[0];
  const float* Wdkv = (const float*)d_in[1];
  const float* Ww = (const float*)d_in[2];
  const float* Wb = (const float*)d_in[3];
  float* outp = (float*)d_out;

  char* ws = (char*)d_ws;
  unsigned short* qB = (unsigned short*)ws;               // 4,718,592 B
  unsigned short* xB = (unsigned short*)(ws + 4718592);   // 16,777,216 B
  unsigned short* wdkvB = (unsigned short*)(ws + 21495808);  // 4,718,592 B
  unsigned short* wwB = (unsigned short*)(ws + 26214400); // 589,824 B
  char* partialB = ws + 26804224;

  int CH = 32, SPB = 32;
  for (int ch = 4; ch < 32; ch *= 2) {
    int spb = 0;
    for (int t = 0; t < 32; ++t) spb += (t + ch) / ch;
    if (26804224 + (size_t)4 * spb * SLOTB <= ws_size) { CH = ch; SPB = spb; break; }
  }

  tobf16<<<5392, 256, 0, stream>>>(x, Wdkv, Ww, xB, wdkvB, wwB);
  qproj<<<384, 256, 0, stream>>>(xB, wwB, Wb, qB);
  attn<<<4 * SPB, 256, 0, stream>>>(wdkvB, qB, outp, partialB, CH, SPB);
  if (CH < 32) reduce_k<<<4 * (32 - CH), 256, 0, stream>>>(partialB, outp, CH, SPB);
}